// Round 9
// baseline (205.012 us; speedup 1.0000x reference)
//
#include <hip/hip_runtime.h>
#include <hip/hip_bf16.h>
#include <math.h>

// Problem constants (reference: B=2, T=2048, D_MODEL=1024, N_HEAD=16, D_HEAD=64)
constexpr int Bb   = 2;
constexpr int T    = 2048;
constexpr int C    = 1024;
constexpr int H    = 16;
constexpr int M    = Bb * T;   // 4096 rows
constexpr int NQKV = 3 * C;    // 3072

typedef __attribute__((ext_vector_type(8))) short bf16x8;
typedef __attribute__((ext_vector_type(4))) float f32x4;

__device__ inline short f2bf(float f) {
    __hip_bfloat16 h = __float2bfloat16(f);
    return *reinterpret_cast<short*>(&h);
}

#if __has_builtin(__builtin_amdgcn_exp2f)
#define EXP2(x) __builtin_amdgcn_exp2f(x)
#else
#define EXP2(x) exp2f(x)
#endif

#define GLOBAL_AS __attribute__((address_space(1)))
#define LDS_AS    __attribute__((address_space(3)))

__device__ __forceinline__ void gload_lds16(const short* g, short* s) {
    __builtin_amdgcn_global_load_lds((const GLOBAL_AS void*)g, (LDS_AS void*)s, 16, 0, 0);
}

// Drain the wave's DS queue and forbid compiler reordering of LDS ops across
// this point. Needed for the per-wave P round-trip (write/read lane maps are
// per-lane disjoint -> compiler may otherwise hoist the read; R7 race).
__device__ __forceinline__ void lds_fence_wave() {
    __asm__ __volatile__("s_waitcnt lgkmcnt(0)" ::: "memory");
}

// ---------------------------------------------------------------------------
// Fused prep: x->bf16 (blocks 0..4095), w_qkv transpose (4096..7167),
// w_proj transpose (7168..8191).
// ---------------------------------------------------------------------------
__global__ __launch_bounds__(256)
void prep_all(const float* __restrict__ x, short* __restrict__ xb,
              const float* __restrict__ w_qkv, short* __restrict__ wqkvt,
              const float* __restrict__ w_proj, short* __restrict__ wprojt)
{
    __shared__ float tile[32][33];
    const int blk = blockIdx.x;
    const int tid = threadIdx.x;

    if (blk < 4096) {                       // cvt x
        const int i = blk * 1024 + tid * 4;
        const float4 v = *(const float4*)(x + i);
        short4 s;
        s.x = f2bf(v.x); s.y = f2bf(v.y); s.z = f2bf(v.z); s.w = f2bf(v.w);
        *(short4*)(xb + i) = s;
        return;
    }

    const bool isqkv = (blk < 7168);
    const int bidx = isqkv ? (blk - 4096) : (blk - 7168);
    const int nblk = isqkv ? 96 : 32;       // N/32
    const int N    = isqkv ? NQKV : C;
    const float* W = isqkv ? w_qkv : w_proj;
    short* Wt      = isqkv ? wqkvt : wprojt;

    const int n0 = (bidx % nblk) * 32, k0 = (bidx / nblk) * 32;
    const int tx = tid & 31, ty = tid >> 5;   // 32 x 8
#pragma unroll
    for (int i = 0; i < 32; i += 8)
        tile[ty + i][tx] = W[(size_t)(k0 + ty + i) * N + n0 + tx];
    __syncthreads();
#pragma unroll
    for (int i = 0; i < 32; i += 8)
        Wt[(size_t)(n0 + ty + i) * C + k0 + tx] = f2bf(tile[tx][ty + i]);
}

// ---------------------------------------------------------------------------
// QKV GEMM: out[M,N] = A @ Bt^T + bias   (128x128 tile, BK=64 -> 16 barrier
// pairs instead of 32; unpadded [128][64] LDS; async staging 8x16B per wave)
// ---------------------------------------------------------------------------
__global__ __launch_bounds__(256)
void gemm_mfma(const short* __restrict__ A, const short* __restrict__ Bt,
               const float* __restrict__ bias, short* __restrict__ outp,
               int Ndim, int Kdim)
{
    __shared__ __align__(16) short As[128 * 64];   // 16 KB
    __shared__ __align__(16) short Bs[128 * 64];   // 16 KB

    const int tid = threadIdx.x;
    const int w   = tid >> 6;
    const int l   = tid & 63;
    const int lk  = l & 15;
    const int lq  = l >> 4;
    const int m0  = blockIdx.y * 128, n0 = blockIdx.x * 128;
    const int mw  = (w >> 1) * 64, nw = (w & 1) * 64;

    // staging: lane l -> row-in-group l>>3, col (l&7)*8; groups of 8 rows
    const int srow = (l >> 3);
    const int scol = (l & 7) * 8;
    const int g0 = w * 16;          // wave's row groups: g0, g0+8, 64+g0, 64+g0+8

    f32x4 acc[4][4];
#pragma unroll
    for (int i = 0; i < 4; ++i)
#pragma unroll
        for (int j = 0; j < 4; ++j) acc[i][j] = (f32x4){0.f, 0.f, 0.f, 0.f};

    for (int k0 = 0; k0 < Kdim; k0 += 64) {
        __syncthreads();
#pragma unroll
        for (int gi = 0; gi < 4; ++gi) {
            const int g = (gi & 1) * 8 + (gi >> 1) * 64 + g0;
            gload_lds16(A  + (size_t)(m0 + g + srow) * Kdim + k0 + scol, &As[g * 64]);
            gload_lds16(Bt + (size_t)(n0 + g + srow) * Kdim + k0 + scol, &Bs[g * 64]);
        }
        __syncthreads();

#pragma unroll
        for (int s = 0; s < 2; ++s) {
            bf16x8 af[4], bfr[4];
#pragma unroll
            for (int mt = 0; mt < 4; ++mt)
                af[mt] = *(const bf16x8*)&As[(mw + mt * 16 + lk) * 64 + s * 32 + lq * 8];
#pragma unroll
            for (int nt = 0; nt < 4; ++nt)
                bfr[nt] = *(const bf16x8*)&Bs[(nw + nt * 16 + lk) * 64 + s * 32 + lq * 8];
#pragma unroll
            for (int mt = 0; mt < 4; ++mt)
#pragma unroll
                for (int nt = 0; nt < 4; ++nt)
                    acc[mt][nt] = __builtin_amdgcn_mfma_f32_16x16x32_bf16(af[mt], bfr[nt], acc[mt][nt], 0, 0, 0);
        }
    }

#pragma unroll
    for (int mt = 0; mt < 4; ++mt) {
#pragma unroll
        for (int nt = 0; nt < 4; ++nt) {
            const int col = n0 + nw + nt * 16 + lk;
            const float bv = bias[col];
#pragma unroll
            for (int r = 0; r < 4; ++r) {
                const int row = m0 + mw + mt * 16 + lq * 4 + r;
                outp[(size_t)row * Ndim + col] = f2bf(acc[mt][nt][r] + bv);
            }
        }
    }
}

// ---------------------------------------------------------------------------
// Proj GEMM: 64x128 tile, BK=64, grid (8,64)=512 blocks. fp32 output.
// ---------------------------------------------------------------------------
__global__ __launch_bounds__(256)
void gemm_mfma_proj(const short* __restrict__ A, const short* __restrict__ Bt,
                    const float* __restrict__ bias, float* __restrict__ outp,
                    int Ndim, int Kdim)
{
    __shared__ __align__(16) short As[64 * 64];    //  8 KB
    __shared__ __align__(16) short Bs[128 * 64];   // 16 KB

    const int tid = threadIdx.x;
    const int w   = tid >> 6;
    const int l   = tid & 63;
    const int lk  = l & 15;
    const int lq  = l >> 4;
    const int m0  = blockIdx.y * 64, n0 = blockIdx.x * 128;
    const int mw  = (w & 1) * 32, nw = (w >> 1) * 64;

    const int srow = (l >> 3);
    const int scol = (l & 7) * 8;
    const int g0 = w * 16;

    f32x4 acc[2][4];
#pragma unroll
    for (int i = 0; i < 2; ++i)
#pragma unroll
        for (int j = 0; j < 4; ++j) acc[i][j] = (f32x4){0.f, 0.f, 0.f, 0.f};

    for (int k0 = 0; k0 < Kdim; k0 += 64) {
        __syncthreads();
#pragma unroll
        for (int gi = 0; gi < 2; ++gi) {             // A: 64 rows
            const int g = g0 + gi * 8;
            gload_lds16(A + (size_t)(m0 + g + srow) * Kdim + k0 + scol, &As[g * 64]);
        }
#pragma unroll
        for (int gi = 0; gi < 4; ++gi) {             // B: 128 rows
            const int g = (gi & 1) * 8 + (gi >> 1) * 64 + g0;
            gload_lds16(Bt + (size_t)(n0 + g + srow) * Kdim + k0 + scol, &Bs[g * 64]);
        }
        __syncthreads();

#pragma unroll
        for (int s = 0; s < 2; ++s) {
            bf16x8 af[2], bfr[4];
#pragma unroll
            for (int mt = 0; mt < 2; ++mt)
                af[mt] = *(const bf16x8*)&As[(mw + mt * 16 + lk) * 64 + s * 32 + lq * 8];
#pragma unroll
            for (int nt = 0; nt < 4; ++nt)
                bfr[nt] = *(const bf16x8*)&Bs[(nw + nt * 16 + lk) * 64 + s * 32 + lq * 8];
#pragma unroll
            for (int mt = 0; mt < 2; ++mt)
#pragma unroll
                for (int nt = 0; nt < 4; ++nt)
                    acc[mt][nt] = __builtin_amdgcn_mfma_f32_16x16x32_bf16(af[mt], bfr[nt], acc[mt][nt], 0, 0, 0);
        }
    }

#pragma unroll
    for (int mt = 0; mt < 2; ++mt) {
#pragma unroll
        for (int nt = 0; nt < 4; ++nt) {
            const int col = n0 + nw + nt * 16 + lk;
            const float bv = bias[col];
#pragma unroll
            for (int r = 0; r < 4; ++r) {
                const int row = m0 + mw + mt * 16 + lq * 4 + r;
                outp[(size_t)row * Ndim + col] = acc[mt][nt][r] + bv;
            }
        }
    }
}

// ---------------------------------------------------------------------------
// MFMA flash attention v6: S^T formulation + 128-key tiles.
// Halves serial iterations and per-iteration fixed costs (barriers, m/l
// update, O rescale, shfl tail) vs v5.1 at identical per-key cost.
// Ks [128][64] async-staged (4x16B per wave); Vt [64][136]; per-wave Ps
// [16][136]. 50 KB LDS -> 3 blocks/CU. Grid 1024, XCD-pinned bh (R5-proven),
// balanced qt permutation (R6-proven). P round-trip fenced (R8 fix).
// ---------------------------------------------------------------------------
constexpr int LDV = 136;   // 128 keys + 8 pad (272 B rows)
constexpr int LDP = 136;
constexpr float SC = 0.18033688f;   // 0.125 * log2(e)

__global__ __launch_bounds__(256)
void attn_mfma(const short* __restrict__ qkv, short* __restrict__ att)
{
    __shared__ __align__(16) short Ks[128 * 64];     // [key][dim]  16 KB
    __shared__ __align__(16) short Vt[64 * LDV];     // [dim][key]  17 KB
    __shared__ __align__(16) short Ps[4][16 * LDP];  // per-wave    17 KB

    const int idx = blockIdx.x;
    const int xcd = idx & 7;
    const int j   = idx >> 3;                // 0..127
    const int bh  = xcd * 4 + (j & 3);
    const int s   = j >> 2;                  // 0..31
    const int qt  = (s < 8)  ? (31 - s)
                  : (s < 16) ? (s - 8)
                  : (s < 24) ? (39 - s)
                  :            (s - 16);
    const int b   = bh >> 4;
    const int h   = bh & 15;
    const int qbase = qt * 64;

    const int tid = threadIdx.x;
    const int w   = tid >> 6;
    const int l   = tid & 63;
    const int lk  = l & 15;
    const int lq  = l >> 4;

    const short* base = qkv + (size_t)b * T * 3072 + h * 64;

    // Q fragments (B-operand of S^T); lane owns q-row q_abs
    const int q_abs = qbase + w * 16 + lk;
    const short* qp = base + (size_t)q_abs * 3072 + lq * 8;
    const bf16x8 qf0 = *(const bf16x8*)qp;
    const bf16x8 qf1 = *(const bf16x8*)(qp + 32);

    // O^T accumulators: acc[dt][r] = O^T[d=dt*16+lq*4+r][q=lk]
    f32x4 acc_o[4];
#pragma unroll
    for (int dt = 0; dt < 4; ++dt) acc_o[dt] = (f32x4){0.f, 0.f, 0.f, 0.f};
    float m_run = -INFINITY;
    float l_run = 0.f;

    // K staging map: wave w rows w*32..+32, lane -> row-in-group l>>3, col (l&7)*8
    const int ksr = l >> 3;
    const int ksc = (l & 7) * 8;

    // V staging map: thread -> keys (tid&31)*4..+4, dims (tid>>5)*8..+8
    const int vkg = (tid & 31) * 4;
    const int vd0 = (tid >> 5) * 8;

    const int nkt = (qbase + 64 + 127) >> 7;
#pragma unroll 1
    for (int it = 0; it < nkt; ++it) {
        const int j0 = it * 128;
        __syncthreads();
#pragma unroll
        for (int rr = 0; rr < 4; ++rr) {
            const int g = w * 32 + rr * 8;
            gload_lds16(base + 1024 + (size_t)(j0 + g + ksr) * 3072 + ksc, &Ks[g * 64]);
        }
        {
            const short* vp = base + 2048 + (size_t)(j0 + vkg) * 3072 + vd0;
            bf16x8 vv[4];
#pragma unroll
            for (int kk = 0; kk < 4; ++kk)
                vv[kk] = *(const bf16x8*)(vp + (size_t)kk * 3072);
#pragma unroll
            for (int d = 0; d < 8; ++d) {
                short4 pk;
                pk.x = vv[0][d]; pk.y = vv[1][d]; pk.z = vv[2][d]; pk.w = vv[3][d];
                *(short4*)&Vt[(vd0 + d) * LDV + vkg] = pk;
            }
        }
        __syncthreads();

        // --- S^T = K Q^T: s4[kt][r] = S[key = j0 + kt*16 + lq*4 + r][q = lk] ---
        f32x4 s4[8];
#pragma unroll
        for (int kt = 0; kt < 8; ++kt) {
            const bf16x8 kf0 = *(const bf16x8*)&Ks[(kt * 16 + lk) * 64 + lq * 8];
            const bf16x8 kf1 = *(const bf16x8*)&Ks[(kt * 16 + lk) * 64 + 32 + lq * 8];
            f32x4 a = (f32x4){0.f, 0.f, 0.f, 0.f};
            a = __builtin_amdgcn_mfma_f32_16x16x32_bf16(kf0, qf0, a, 0, 0, 0);
            a = __builtin_amdgcn_mfma_f32_16x16x32_bf16(kf1, qf1, a, 0, 0, 0);
            s4[kt] = a;
        }

        // --- causal mask (last tile only; raw scores) ---
        if (it == nkt - 1) {
#pragma unroll
            for (int kt = 0; kt < 8; ++kt)
#pragma unroll
                for (int r = 0; r < 4; ++r)
                    if (j0 + kt * 16 + lq * 4 + r > q_abs) s4[kt][r] = -1e30f;
        }

        // --- online softmax: in-lane tree over 32 + 2 shfl hops ---
        float mx = s4[0][0];
#pragma unroll
        for (int kt = 0; kt < 8; ++kt)
#pragma unroll
            for (int r = 0; r < 4; ++r) mx = fmaxf(mx, s4[kt][r]);
        mx = fmaxf(mx, __shfl_xor(mx, 16));
        mx = fmaxf(mx, __shfl_xor(mx, 32));
        const float mn   = fmaxf(m_run, mx);
        const float corr = EXP2((m_run - mn) * SC);
        m_run = mn;
        const float nmc = -mn * SC;
#pragma unroll
        for (int kt = 0; kt < 8; ++kt)
#pragma unroll
            for (int r = 0; r < 4; ++r)
                s4[kt][r] = EXP2(fmaf(s4[kt][r], SC, nmc));
        float ps = 0.f;
#pragma unroll
        for (int kt = 0; kt < 8; ++kt)
            ps += ((s4[kt][0] + s4[kt][1]) + (s4[kt][2] + s4[kt][3]));
        ps += __shfl_xor(ps, 16);
        ps += __shfl_xor(ps, 32);
        l_run = l_run * corr + ps;

        // --- P[q][key] -> per-wave LDS (packed b32 writes) ---
        short* myP = &Ps[w][0];
#pragma unroll
        for (int kt = 0; kt < 8; ++kt) {
            const unsigned int p01 = (unsigned int)(unsigned short)f2bf(s4[kt][0])
                                   | ((unsigned int)(unsigned short)f2bf(s4[kt][1]) << 16);
            const unsigned int p23 = (unsigned int)(unsigned short)f2bf(s4[kt][2])
                                   | ((unsigned int)(unsigned short)f2bf(s4[kt][3]) << 16);
            *(unsigned int*)&myP[lk * LDP + kt * 16 + lq * 4]     = p01;
            *(unsigned int*)&myP[lk * LDP + kt * 16 + lq * 4 + 2] = p23;
        }

        lds_fence_wave();   // order cross-lane P write->read within the wave

#pragma unroll
        for (int dt = 0; dt < 4; ++dt)
#pragma unroll
            for (int r = 0; r < 4; ++r) acc_o[dt][r] *= corr;

        // --- O^T += V^T P^T (128 keys as four 32-key chunks) ---
#pragma unroll
        for (int kc = 0; kc < 4; ++kc) {
            const bf16x8 pf = *(const bf16x8*)&myP[lk * LDP + kc * 32 + lq * 8];
#pragma unroll
            for (int dt = 0; dt < 4; ++dt) {
                const bf16x8 vf = *(const bf16x8*)&Vt[(dt * 16 + lk) * LDV + kc * 32 + lq * 8];
                acc_o[dt] = __builtin_amdgcn_mfma_f32_16x16x32_bf16(vf, pf, acc_o[dt], 0, 0, 0);
            }
        }
    }

    // --- epilogue: O[q][d] = O^T[d][q]/l ---
    const float inv = 1.f / l_run;
    short* op = att + ((size_t)(b * T + q_abs)) * 1024 + h * 64;
#pragma unroll
    for (int dt = 0; dt < 4; ++dt) {
        short4 pk;
        pk.x = f2bf(acc_o[dt][0] * inv);
        pk.y = f2bf(acc_o[dt][1] * inv);
        pk.z = f2bf(acc_o[dt][2] * inv);
        pk.w = f2bf(acc_o[dt][3] * inv);
        *(short4*)(op + dt * 16 + lq * 4) = pk;
    }
}

// ---------------------------------------------------------------------------
extern "C" void kernel_launch(void* const* d_in, const int* in_sizes, int n_in,
                              void* d_out, int out_size, void* d_ws, size_t ws_size,
                              hipStream_t stream)
{
    const float* x      = (const float*)d_in[0];   // [B,T,C]
    const float* w_qkv  = (const float*)d_in[1];   // [C,3C]
    const float* b_qkv  = (const float*)d_in[2];   // [3C]
    const float* w_proj = (const float*)d_in[3];   // [C,C]
    const float* b_proj = (const float*)d_in[4];   // [C]
    float* out = (float*)d_out;                    // [B,T,C] fp32

    short* xb     = (short*)d_ws;                        //  8 MB
    short* wqkvt  = xb     + (size_t)M * C;              //  6 MB  [3072][1024]
    short* wprojt = wqkvt  + (size_t)NQKV * C;           //  2 MB  [1024][1024]
    short* qkvb   = wprojt + (size_t)C * C;              // 24 MB  [4096][3072]
    short* attb   = qkvb   + (size_t)M * NQKV;           //  8 MB  [4096][1024]

    prep_all<<<8192, 256, 0, stream>>>(x, xb, w_qkv, wqkvt, w_proj, wprojt);
    gemm_mfma<<<dim3(NQKV / 128, M / 128), 256, 0, stream>>>(xb, wqkvt, b_qkv, qkvb, NQKV, C);
    attn_mfma<<<1024, 256, 0, stream>>>(qkvb, attb);
    gemm_mfma_proj<<<dim3(C / 128, M / 64), 256, 0, stream>>>(attb, wprojt, b_proj, out, C, C);
}

// Round 10
// 197.761 us; speedup vs baseline: 1.0367x; 1.0367x over previous
//
#include <hip/hip_runtime.h>
#include <hip/hip_bf16.h>
#include <math.h>

// Problem constants (reference: B=2, T=2048, D_MODEL=1024, N_HEAD=16, D_HEAD=64)
constexpr int Bb   = 2;
constexpr int T    = 2048;
constexpr int C    = 1024;
constexpr int H    = 16;
constexpr int M    = Bb * T;   // 4096 rows
constexpr int NQKV = 3 * C;    // 3072

typedef __attribute__((ext_vector_type(8))) short bf16x8;
typedef __attribute__((ext_vector_type(4))) float f32x4;

__device__ inline short f2bf(float f) {
    __hip_bfloat16 h = __float2bfloat16(f);
    return *reinterpret_cast<short*>(&h);
}

#if __has_builtin(__builtin_amdgcn_exp2f)
#define EXP2(x) __builtin_amdgcn_exp2f(x)
#else
#define EXP2(x) exp2f(x)
#endif

#define GLOBAL_AS __attribute__((address_space(1)))
#define LDS_AS    __attribute__((address_space(3)))

__device__ __forceinline__ void gload_lds16(const short* g, short* s) {
    __builtin_amdgcn_global_load_lds((const GLOBAL_AS void*)g, (LDS_AS void*)s, 16, 0, 0);
}

// Drain the wave's DS queue and forbid compiler reordering of LDS ops across
// this point (R7 race fix for the per-wave P round-trip).
__device__ __forceinline__ void lds_fence_wave() {
    __asm__ __volatile__("s_waitcnt lgkmcnt(0)" ::: "memory");
}

// ---------------------------------------------------------------------------
// Fused prep: x->bf16 (blocks 0..4095), w_qkv transpose (4096..7167),
// w_proj transpose (7168..8191).
// ---------------------------------------------------------------------------
__global__ __launch_bounds__(256)
void prep_all(const float* __restrict__ x, short* __restrict__ xb,
              const float* __restrict__ w_qkv, short* __restrict__ wqkvt,
              const float* __restrict__ w_proj, short* __restrict__ wprojt)
{
    __shared__ float tile[32][33];
    const int blk = blockIdx.x;
    const int tid = threadIdx.x;

    if (blk < 4096) {                       // cvt x
        const int i = blk * 1024 + tid * 4;
        const float4 v = *(const float4*)(x + i);
        short4 s;
        s.x = f2bf(v.x); s.y = f2bf(v.y); s.z = f2bf(v.z); s.w = f2bf(v.w);
        *(short4*)(xb + i) = s;
        return;
    }

    const bool isqkv = (blk < 7168);
    const int bidx = isqkv ? (blk - 4096) : (blk - 7168);
    const int nblk = isqkv ? 96 : 32;       // N/32
    const int N    = isqkv ? NQKV : C;
    const float* W = isqkv ? w_qkv : w_proj;
    short* Wt      = isqkv ? wqkvt : wprojt;

    const int n0 = (bidx % nblk) * 32, k0 = (bidx / nblk) * 32;
    const int tx = tid & 31, ty = tid >> 5;   // 32 x 8
#pragma unroll
    for (int i = 0; i < 32; i += 8)
        tile[ty + i][tx] = W[(size_t)(k0 + ty + i) * N + n0 + tx];
    __syncthreads();
#pragma unroll
    for (int i = 0; i < 32; i += 8)
        Wt[(size_t)(n0 + ty + i) * C + k0 + tx] = f2bf(tile[tx][ty + i]);
}

// ---------------------------------------------------------------------------
// QKV GEMM: out[M,N] = A @ Bt^T + bias.  128x128 tile, BK=32 (m97 layout,
// 64 B LDS rows -> 2-way-max bank aliasing), async 16B staging.
// MFMA operands SWAPPED: mfma(bfr, af) -> n in quad dim, m in lane dim, so
// each thread owns 4 consecutive output columns -> short4 epilogue stores
// (16 b64 stores/thread instead of 64 scalar b16).
// ---------------------------------------------------------------------------
__global__ __launch_bounds__(256)
void gemm_mfma(const short* __restrict__ A, const short* __restrict__ Bt,
               const float* __restrict__ bias, short* __restrict__ outp,
               int Ndim, int Kdim)
{
    __shared__ __align__(16) short As[128 * 32];   // 8 KB
    __shared__ __align__(16) short Bs[128 * 32];   // 8 KB

    const int tid = threadIdx.x;
    const int w   = tid >> 6;
    const int l   = tid & 63;
    const int lk  = l & 15;
    const int lq  = l >> 4;
    const int m0  = blockIdx.y * 128, n0 = blockIdx.x * 128;
    const int mw  = (w >> 1) * 64, nw = (w & 1) * 64;

    const int srow = w * 16 + (l >> 2);
    const int scol = (l & 3) * 8;
    short* asdst0 = &As[w * 512];
    short* asdst1 = &As[2048 + w * 512];
    short* bsdst0 = &Bs[w * 512];
    short* bsdst1 = &Bs[2048 + w * 512];

    f32x4 acc[4][4];
#pragma unroll
    for (int i = 0; i < 4; ++i)
#pragma unroll
        for (int j = 0; j < 4; ++j) acc[i][j] = (f32x4){0.f, 0.f, 0.f, 0.f};

    for (int k0 = 0; k0 < Kdim; k0 += 32) {
        __syncthreads();
        gload_lds16(A  + (size_t)(m0 + srow)      * Kdim + k0 + scol, asdst0);
        gload_lds16(A  + (size_t)(m0 + 64 + srow) * Kdim + k0 + scol, asdst1);
        gload_lds16(Bt + (size_t)(n0 + srow)      * Kdim + k0 + scol, bsdst0);
        gload_lds16(Bt + (size_t)(n0 + 64 + srow) * Kdim + k0 + scol, bsdst1);
        __syncthreads();

        bf16x8 af[4], bfr[4];
#pragma unroll
        for (int mt = 0; mt < 4; ++mt)
            af[mt] = *(const bf16x8*)&As[(mw + mt * 16 + lk) * 32 + lq * 8];
#pragma unroll
        for (int nt = 0; nt < 4; ++nt)
            bfr[nt] = *(const bf16x8*)&Bs[(nw + nt * 16 + lk) * 32 + lq * 8];
#pragma unroll
        for (int mt = 0; mt < 4; ++mt)
#pragma unroll
            for (int nt = 0; nt < 4; ++nt)   // swapped: n -> quads, m -> lanes
                acc[mt][nt] = __builtin_amdgcn_mfma_f32_16x16x32_bf16(bfr[nt], af[mt], acc[mt][nt], 0, 0, 0);
    }

    // epilogue: acc[mt][nt][r] = out[m0+mw+mt*16+lk][n0+nw+nt*16+lq*4+r]
    float4 bv[4];
#pragma unroll
    for (int nt = 0; nt < 4; ++nt)
        bv[nt] = *(const float4*)(bias + n0 + nw + nt * 16 + lq * 4);
#pragma unroll
    for (int mt = 0; mt < 4; ++mt) {
        short* rowp = outp + (size_t)(m0 + mw + mt * 16 + lk) * Ndim + n0 + nw + lq * 4;
#pragma unroll
        for (int nt = 0; nt < 4; ++nt) {
            short4 pk;
            pk.x = f2bf(acc[mt][nt][0] + bv[nt].x);
            pk.y = f2bf(acc[mt][nt][1] + bv[nt].y);
            pk.z = f2bf(acc[mt][nt][2] + bv[nt].z);
            pk.w = f2bf(acc[mt][nt][3] + bv[nt].w);
            *(short4*)(rowp + nt * 16) = pk;
        }
    }
}

// ---------------------------------------------------------------------------
// Proj GEMM: 64x128 tile, BK=32, grid (8,64)=512 blocks. Swapped-operand
// epilogue -> per-thread float4 (16 B) stores. fp32 output.
// ---------------------------------------------------------------------------
__global__ __launch_bounds__(256)
void gemm_mfma_proj(const short* __restrict__ A, const short* __restrict__ Bt,
                    const float* __restrict__ bias, float* __restrict__ outp,
                    int Ndim, int Kdim)
{
    __shared__ __align__(16) short As[64 * 32];    // 4 KB
    __shared__ __align__(16) short Bs[128 * 32];   // 8 KB

    const int tid = threadIdx.x;
    const int w   = tid >> 6;
    const int l   = tid & 63;
    const int lk  = l & 15;
    const int lq  = l >> 4;
    const int m0  = blockIdx.y * 64, n0 = blockIdx.x * 128;
    const int mw  = (w & 1) * 32, nw = (w >> 1) * 64;

    const int srow = w * 16 + (l >> 2);
    const int scol = (l & 3) * 8;
    short* asdst  = &As[w * 512];
    short* bsdst0 = &Bs[w * 512];
    short* bsdst1 = &Bs[2048 + w * 512];

    f32x4 acc[2][4];
#pragma unroll
    for (int i = 0; i < 2; ++i)
#pragma unroll
        for (int j = 0; j < 4; ++j) acc[i][j] = (f32x4){0.f, 0.f, 0.f, 0.f};

    for (int k0 = 0; k0 < Kdim; k0 += 32) {
        __syncthreads();
        gload_lds16(A  + (size_t)(m0 + srow)      * Kdim + k0 + scol, asdst);
        gload_lds16(Bt + (size_t)(n0 + srow)      * Kdim + k0 + scol, bsdst0);
        gload_lds16(Bt + (size_t)(n0 + 64 + srow) * Kdim + k0 + scol, bsdst1);
        __syncthreads();

        bf16x8 af[2], bfr[4];
#pragma unroll
        for (int mt = 0; mt < 2; ++mt)
            af[mt] = *(const bf16x8*)&As[(mw + mt * 16 + lk) * 32 + lq * 8];
#pragma unroll
        for (int nt = 0; nt < 4; ++nt)
            bfr[nt] = *(const bf16x8*)&Bs[(nw + nt * 16 + lk) * 32 + lq * 8];
#pragma unroll
        for (int mt = 0; mt < 2; ++mt)
#pragma unroll
            for (int nt = 0; nt < 4; ++nt)   // swapped: n -> quads, m -> lanes
                acc[mt][nt] = __builtin_amdgcn_mfma_f32_16x16x32_bf16(bfr[nt], af[mt], acc[mt][nt], 0, 0, 0);
    }

    float4 bv[4];
#pragma unroll
    for (int nt = 0; nt < 4; ++nt)
        bv[nt] = *(const float4*)(bias + n0 + nw + nt * 16 + lq * 4);
#pragma unroll
    for (int mt = 0; mt < 2; ++mt) {
        float* rowp = outp + (size_t)(m0 + mw + mt * 16 + lk) * Ndim + n0 + nw + lq * 4;
#pragma unroll
        for (int nt = 0; nt < 4; ++nt) {
            float4 v;
            v.x = acc[mt][nt][0] + bv[nt].x;
            v.y = acc[mt][nt][1] + bv[nt].y;
            v.z = acc[mt][nt][2] + bv[nt].z;
            v.w = acc[mt][nt][3] + bv[nt].w;
            *(float4*)(rowp + nt * 16) = v;
        }
    }
}

// ---------------------------------------------------------------------------
// MFMA flash attention v6 (unchanged from R9): S^T formulation + 128-key
// tiles, async K staging, XCD-pinned bh, balanced qt permutation, fenced
// P round-trip.
// ---------------------------------------------------------------------------
constexpr int LDV = 136;   // 128 keys + 8 pad (272 B rows)
constexpr int LDP = 136;
constexpr float SC = 0.18033688f;   // 0.125 * log2(e)

__global__ __launch_bounds__(256)
void attn_mfma(const short* __restrict__ qkv, short* __restrict__ att)
{
    __shared__ __align__(16) short Ks[128 * 64];     // [key][dim]  16 KB
    __shared__ __align__(16) short Vt[64 * LDV];     // [dim][key]  17 KB
    __shared__ __align__(16) short Ps[4][16 * LDP];  // per-wave    17 KB

    const int idx = blockIdx.x;
    const int xcd = idx & 7;
    const int j   = idx >> 3;                // 0..127
    const int bh  = xcd * 4 + (j & 3);
    const int s   = j >> 2;                  // 0..31
    const int qt  = (s < 8)  ? (31 - s)
                  : (s < 16) ? (s - 8)
                  : (s < 24) ? (39 - s)
                  :            (s - 16);
    const int b   = bh >> 4;
    const int h   = bh & 15;
    const int qbase = qt * 64;

    const int tid = threadIdx.x;
    const int w   = tid >> 6;
    const int l   = tid & 63;
    const int lk  = l & 15;
    const int lq  = l >> 4;

    const short* base = qkv + (size_t)b * T * 3072 + h * 64;

    const int q_abs = qbase + w * 16 + lk;
    const short* qp = base + (size_t)q_abs * 3072 + lq * 8;
    const bf16x8 qf0 = *(const bf16x8*)qp;
    const bf16x8 qf1 = *(const bf16x8*)(qp + 32);

    f32x4 acc_o[4];
#pragma unroll
    for (int dt = 0; dt < 4; ++dt) acc_o[dt] = (f32x4){0.f, 0.f, 0.f, 0.f};
    float m_run = -INFINITY;
    float l_run = 0.f;

    const int ksr = l >> 3;
    const int ksc = (l & 7) * 8;

    const int vkg = (tid & 31) * 4;
    const int vd0 = (tid >> 5) * 8;

    const int nkt = (qbase + 64 + 127) >> 7;
#pragma unroll 1
    for (int it = 0; it < nkt; ++it) {
        const int j0 = it * 128;
        __syncthreads();
#pragma unroll
        for (int rr = 0; rr < 4; ++rr) {
            const int g = w * 32 + rr * 8;
            gload_lds16(base + 1024 + (size_t)(j0 + g + ksr) * 3072 + ksc, &Ks[g * 64]);
        }
        {
            const short* vp = base + 2048 + (size_t)(j0 + vkg) * 3072 + vd0;
            bf16x8 vv[4];
#pragma unroll
            for (int kk = 0; kk < 4; ++kk)
                vv[kk] = *(const bf16x8*)(vp + (size_t)kk * 3072);
#pragma unroll
            for (int d = 0; d < 8; ++d) {
                short4 pk;
                pk.x = vv[0][d]; pk.y = vv[1][d]; pk.z = vv[2][d]; pk.w = vv[3][d];
                *(short4*)&Vt[(vd0 + d) * LDV + vkg] = pk;
            }
        }
        __syncthreads();

        f32x4 s4[8];
#pragma unroll
        for (int kt = 0; kt < 8; ++kt) {
            const bf16x8 kf0 = *(const bf16x8*)&Ks[(kt * 16 + lk) * 64 + lq * 8];
            const bf16x8 kf1 = *(const bf16x8*)&Ks[(kt * 16 + lk) * 64 + 32 + lq * 8];
            f32x4 a = (f32x4){0.f, 0.f, 0.f, 0.f};
            a = __builtin_amdgcn_mfma_f32_16x16x32_bf16(kf0, qf0, a, 0, 0, 0);
            a = __builtin_amdgcn_mfma_f32_16x16x32_bf16(kf1, qf1, a, 0, 0, 0);
            s4[kt] = a;
        }

        if (it == nkt - 1) {
#pragma unroll
            for (int kt = 0; kt < 8; ++kt)
#pragma unroll
                for (int r = 0; r < 4; ++r)
                    if (j0 + kt * 16 + lq * 4 + r > q_abs) s4[kt][r] = -1e30f;
        }

        float mx = s4[0][0];
#pragma unroll
        for (int kt = 0; kt < 8; ++kt)
#pragma unroll
            for (int r = 0; r < 4; ++r) mx = fmaxf(mx, s4[kt][r]);
        mx = fmaxf(mx, __shfl_xor(mx, 16));
        mx = fmaxf(mx, __shfl_xor(mx, 32));
        const float mn   = fmaxf(m_run, mx);
        const float corr = EXP2((m_run - mn) * SC);
        m_run = mn;
        const float nmc = -mn * SC;
#pragma unroll
        for (int kt = 0; kt < 8; ++kt)
#pragma unroll
            for (int r = 0; r < 4; ++r)
                s4[kt][r] = EXP2(fmaf(s4[kt][r], SC, nmc));
        float ps = 0.f;
#pragma unroll
        for (int kt = 0; kt < 8; ++kt)
            ps += ((s4[kt][0] + s4[kt][1]) + (s4[kt][2] + s4[kt][3]));
        ps += __shfl_xor(ps, 16);
        ps += __shfl_xor(ps, 32);
        l_run = l_run * corr + ps;

        short* myP = &Ps[w][0];
#pragma unroll
        for (int kt = 0; kt < 8; ++kt) {
            const unsigned int p01 = (unsigned int)(unsigned short)f2bf(s4[kt][0])
                                   | ((unsigned int)(unsigned short)f2bf(s4[kt][1]) << 16);
            const unsigned int p23 = (unsigned int)(unsigned short)f2bf(s4[kt][2])
                                   | ((unsigned int)(unsigned short)f2bf(s4[kt][3]) << 16);
            *(unsigned int*)&myP[lk * LDP + kt * 16 + lq * 4]     = p01;
            *(unsigned int*)&myP[lk * LDP + kt * 16 + lq * 4 + 2] = p23;
        }

        lds_fence_wave();

#pragma unroll
        for (int dt = 0; dt < 4; ++dt)
#pragma unroll
            for (int r = 0; r < 4; ++r) acc_o[dt][r] *= corr;

#pragma unroll
        for (int kc = 0; kc < 4; ++kc) {
            const bf16x8 pf = *(const bf16x8*)&myP[lk * LDP + kc * 32 + lq * 8];
#pragma unroll
            for (int dt = 0; dt < 4; ++dt) {
                const bf16x8 vf = *(const bf16x8*)&Vt[(dt * 16 + lk) * LDV + kc * 32 + lq * 8];
                acc_o[dt] = __builtin_amdgcn_mfma_f32_16x16x32_bf16(vf, pf, acc_o[dt], 0, 0, 0);
            }
        }
    }

    const float inv = 1.f / l_run;
    short* op = att + ((size_t)(b * T + q_abs)) * 1024 + h * 64;
#pragma unroll
    for (int dt = 0; dt < 4; ++dt) {
        short4 pk;
        pk.x = f2bf(acc_o[dt][0] * inv);
        pk.y = f2bf(acc_o[dt][1] * inv);
        pk.z = f2bf(acc_o[dt][2] * inv);
        pk.w = f2bf(acc_o[dt][3] * inv);
        *(short4*)(op + dt * 16 + lq * 4) = pk;
    }
}

// ---------------------------------------------------------------------------
extern "C" void kernel_launch(void* const* d_in, const int* in_sizes, int n_in,
                              void* d_out, int out_size, void* d_ws, size_t ws_size,
                              hipStream_t stream)
{
    const float* x      = (const float*)d_in[0];   // [B,T,C]
    const float* w_qkv  = (const float*)d_in[1];   // [C,3C]
    const float* b_qkv  = (const float*)d_in[2];   // [3C]
    const float* w_proj = (const float*)d_in[3];   // [C,C]
    const float* b_proj = (const float*)d_in[4];   // [C]
    float* out = (float*)d_out;                    // [B,T,C] fp32

    short* xb     = (short*)d_ws;                        //  8 MB
    short* wqkvt  = xb     + (size_t)M * C;              //  6 MB  [3072][1024]
    short* wprojt = wqkvt  + (size_t)NQKV * C;           //  2 MB  [1024][1024]
    short* qkvb   = wprojt + (size_t)C * C;              // 24 MB  [4096][3072]
    short* attb   = qkvb   + (size_t)M * NQKV;           //  8 MB  [4096][1024]

    prep_all<<<8192, 256, 0, stream>>>(x, xb, w_qkv, wqkvt, w_proj, wprojt);
    gemm_mfma<<<dim3(NQKV / 128, M / 128), 256, 0, stream>>>(xb, wqkvt, b_qkv, qkvb, NQKV, C);
    attn_mfma<<<1024, 256, 0, stream>>>(qkvb, attb);
    gemm_mfma_proj<<<dim3(C / 128, M / 64), 256, 0, stream>>>(attb, wprojt, b_proj, out, C, C);
}

// Round 12
// 188.810 us; speedup vs baseline: 1.0858x; 1.0474x over previous
//
#include <hip/hip_runtime.h>
#include <hip/hip_bf16.h>
#include <math.h>

// Problem constants (reference: B=2, T=2048, D_MODEL=1024, N_HEAD=16, D_HEAD=64)
constexpr int Bb   = 2;
constexpr int T    = 2048;
constexpr int C    = 1024;
constexpr int H    = 16;
constexpr int M    = Bb * T;   // 4096 rows
constexpr int NQKV = 3 * C;    // 3072

typedef __attribute__((ext_vector_type(8))) short bf16x8;
typedef __attribute__((ext_vector_type(4))) float f32x4;

__device__ inline short f2bf(float f) {
    __hip_bfloat16 h = __float2bfloat16(f);
    return *reinterpret_cast<short*>(&h);
}

#if __has_builtin(__builtin_amdgcn_exp2f)
#define EXP2(x) __builtin_amdgcn_exp2f(x)
#else
#define EXP2(x) exp2f(x)
#endif

#define GLOBAL_AS __attribute__((address_space(1)))
#define LDS_AS    __attribute__((address_space(3)))

__device__ __forceinline__ void gload_lds16(const short* g, short* s) {
    __builtin_amdgcn_global_load_lds((const GLOBAL_AS void*)g, (LDS_AS void*)s, 16, 0, 0);
}

// ---------------------------------------------------------------------------
// Fused prep: x->bf16 (blocks 0..4095), w_qkv transpose (4096..7167),
// w_proj transpose (7168..8191).
// ---------------------------------------------------------------------------
__global__ __launch_bounds__(256)
void prep_all(const float* __restrict__ x, short* __restrict__ xb,
              const float* __restrict__ w_qkv, short* __restrict__ wqkvt,
              const float* __restrict__ w_proj, short* __restrict__ wprojt)
{
    __shared__ float tile[32][33];
    const int blk = blockIdx.x;
    const int tid = threadIdx.x;

    if (blk < 4096) {                       // cvt x
        const int i = blk * 1024 + tid * 4;
        const float4 v = *(const float4*)(x + i);
        short4 s;
        s.x = f2bf(v.x); s.y = f2bf(v.y); s.z = f2bf(v.z); s.w = f2bf(v.w);
        *(short4*)(xb + i) = s;
        return;
    }

    const bool isqkv = (blk < 7168);
    const int bidx = isqkv ? (blk - 4096) : (blk - 7168);
    const int nblk = isqkv ? 96 : 32;       // N/32
    const int N    = isqkv ? NQKV : C;
    const float* W = isqkv ? w_qkv : w_proj;
    short* Wt      = isqkv ? wqkvt : wprojt;

    const int n0 = (bidx % nblk) * 32, k0 = (bidx / nblk) * 32;
    const int tx = tid & 31, ty = tid >> 5;   // 32 x 8
#pragma unroll
    for (int i = 0; i < 32; i += 8)
        tile[ty + i][tx] = W[(size_t)(k0 + ty + i) * N + n0 + tx];
    __syncthreads();
#pragma unroll
    for (int i = 0; i < 32; i += 8)
        Wt[(size_t)(n0 + ty + i) * C + k0 + tx] = f2bf(tile[tx][ty + i]);
}

// ---------------------------------------------------------------------------
// QKV GEMM: 128x128 tile, BK=32 (m97 layout), async 16B staging, swapped-
// operand epilogue (short4 stores). Unchanged from R10.
// ---------------------------------------------------------------------------
__global__ __launch_bounds__(256)
void gemm_mfma(const short* __restrict__ A, const short* __restrict__ Bt,
               const float* __restrict__ bias, short* __restrict__ outp,
               int Ndim, int Kdim)
{
    __shared__ __align__(16) short As[128 * 32];   // 8 KB
    __shared__ __align__(16) short Bs[128 * 32];   // 8 KB

    const int tid = threadIdx.x;
    const int w   = tid >> 6;
    const int l   = tid & 63;
    const int lk  = l & 15;
    const int lq  = l >> 4;
    const int m0  = blockIdx.y * 128, n0 = blockIdx.x * 128;
    const int mw  = (w >> 1) * 64, nw = (w & 1) * 64;

    const int srow = w * 16 + (l >> 2);
    const int scol = (l & 3) * 8;
    short* asdst0 = &As[w * 512];
    short* asdst1 = &As[2048 + w * 512];
    short* bsdst0 = &Bs[w * 512];
    short* bsdst1 = &Bs[2048 + w * 512];

    f32x4 acc[4][4];
#pragma unroll
    for (int i = 0; i < 4; ++i)
#pragma unroll
        for (int j = 0; j < 4; ++j) acc[i][j] = (f32x4){0.f, 0.f, 0.f, 0.f};

    for (int k0 = 0; k0 < Kdim; k0 += 32) {
        __syncthreads();
        gload_lds16(A  + (size_t)(m0 + srow)      * Kdim + k0 + scol, asdst0);
        gload_lds16(A  + (size_t)(m0 + 64 + srow) * Kdim + k0 + scol, asdst1);
        gload_lds16(Bt + (size_t)(n0 + srow)      * Kdim + k0 + scol, bsdst0);
        gload_lds16(Bt + (size_t)(n0 + 64 + srow) * Kdim + k0 + scol, bsdst1);
        __syncthreads();

        bf16x8 af[4], bfr[4];
#pragma unroll
        for (int mt = 0; mt < 4; ++mt)
            af[mt] = *(const bf16x8*)&As[(mw + mt * 16 + lk) * 32 + lq * 8];
#pragma unroll
        for (int nt = 0; nt < 4; ++nt)
            bfr[nt] = *(const bf16x8*)&Bs[(nw + nt * 16 + lk) * 32 + lq * 8];
#pragma unroll
        for (int mt = 0; mt < 4; ++mt)
#pragma unroll
            for (int nt = 0; nt < 4; ++nt)   // swapped: n -> quads, m -> lanes
                acc[mt][nt] = __builtin_amdgcn_mfma_f32_16x16x32_bf16(bfr[nt], af[mt], acc[mt][nt], 0, 0, 0);
    }

    float4 bv[4];
#pragma unroll
    for (int nt = 0; nt < 4; ++nt)
        bv[nt] = *(const float4*)(bias + n0 + nw + nt * 16 + lq * 4);
#pragma unroll
    for (int mt = 0; mt < 4; ++mt) {
        short* rowp = outp + (size_t)(m0 + mw + mt * 16 + lk) * Ndim + n0 + nw + lq * 4;
#pragma unroll
        for (int nt = 0; nt < 4; ++nt) {
            short4 pk;
            pk.x = f2bf(acc[mt][nt][0] + bv[nt].x);
            pk.y = f2bf(acc[mt][nt][1] + bv[nt].y);
            pk.z = f2bf(acc[mt][nt][2] + bv[nt].z);
            pk.w = f2bf(acc[mt][nt][3] + bv[nt].w);
            *(short4*)(rowp + nt * 16) = pk;
        }
    }
}

// ---------------------------------------------------------------------------
// Proj GEMM: 64x128 tile, BK=32, grid (8,64)=512 blocks. Unchanged from R10.
// ---------------------------------------------------------------------------
__global__ __launch_bounds__(256)
void gemm_mfma_proj(const short* __restrict__ A, const short* __restrict__ Bt,
                    const float* __restrict__ bias, float* __restrict__ outp,
                    int Ndim, int Kdim)
{
    __shared__ __align__(16) short As[64 * 32];    // 4 KB
    __shared__ __align__(16) short Bs[128 * 32];   // 8 KB

    const int tid = threadIdx.x;
    const int w   = tid >> 6;
    const int l   = tid & 63;
    const int lk  = l & 15;
    const int lq  = l >> 4;
    const int m0  = blockIdx.y * 64, n0 = blockIdx.x * 128;
    const int mw  = (w & 1) * 32, nw = (w >> 1) * 64;

    const int srow = w * 16 + (l >> 2);
    const int scol = (l & 3) * 8;
    short* asdst  = &As[w * 512];
    short* bsdst0 = &Bs[w * 512];
    short* bsdst1 = &Bs[2048 + w * 512];

    f32x4 acc[2][4];
#pragma unroll
    for (int i = 0; i < 2; ++i)
#pragma unroll
        for (int j = 0; j < 4; ++j) acc[i][j] = (f32x4){0.f, 0.f, 0.f, 0.f};

    for (int k0 = 0; k0 < Kdim; k0 += 32) {
        __syncthreads();
        gload_lds16(A  + (size_t)(m0 + srow)      * Kdim + k0 + scol, asdst);
        gload_lds16(Bt + (size_t)(n0 + srow)      * Kdim + k0 + scol, bsdst0);
        gload_lds16(Bt + (size_t)(n0 + 64 + srow) * Kdim + k0 + scol, bsdst1);
        __syncthreads();

        bf16x8 af[2], bfr[4];
#pragma unroll
        for (int mt = 0; mt < 2; ++mt)
            af[mt] = *(const bf16x8*)&As[(mw + mt * 16 + lk) * 32 + lq * 8];
#pragma unroll
        for (int nt = 0; nt < 4; ++nt)
            bfr[nt] = *(const bf16x8*)&Bs[(nw + nt * 16 + lk) * 32 + lq * 8];
#pragma unroll
        for (int mt = 0; mt < 2; ++mt)
#pragma unroll
            for (int nt = 0; nt < 4; ++nt)
                acc[mt][nt] = __builtin_amdgcn_mfma_f32_16x16x32_bf16(bfr[nt], af[mt], acc[mt][nt], 0, 0, 0);
    }

    float4 bv[4];
#pragma unroll
    for (int nt = 0; nt < 4; ++nt)
        bv[nt] = *(const float4*)(bias + n0 + nw + nt * 16 + lq * 4);
#pragma unroll
    for (int mt = 0; mt < 2; ++mt) {
        float* rowp = outp + (size_t)(m0 + mw + mt * 16 + lk) * Ndim + n0 + nw + lq * 4;
#pragma unroll
        for (int nt = 0; nt < 4; ++nt) {
            float4 v;
            v.x = acc[mt][nt][0] + bv[nt].x;
            v.y = acc[mt][nt][1] + bv[nt].y;
            v.z = acc[mt][nt][2] + bv[nt].z;
            v.w = acc[mt][nt][3] + bv[nt].w;
            *(float4*)(rowp + nt * 16) = v;
        }
    }
}

// ---------------------------------------------------------------------------
// MFMA flash attention v8: S^T formulation, 128-key tiles, register-direct PV.
//  - PV trick: MFMA is key-order agnostic if A and B agree on the key<->slot
//    map. Slot (lq,j) of chunk kc := key kc*32 + (j>>2)*16 + lq*4 + (j&3).
//    Then pf = {s4[2kc][0..3], s4[2kc+1][0..3]} STRAIGHT from registers
//    (C-layout is exactly this), and V is staged into Vt with the matching
//    granule permutation so vf stays one b128 read. No P LDS / fence / shfl.
//  - Ks [128][64] XOR-swizzled at 16B granules (raw layout put every row at
//    bank 0 -> R10's 1.06e7 conflicts): stage col (l&7)^(l>>3), read
//    col block lq^(lk&7).
//  - LDS 33 KB -> 4 blocks/CU (16 waves); grid 1024 fully resident;
//    XCD-pinned bh + exact balanced qt permutation.
// ---------------------------------------------------------------------------
constexpr int LDV = 136;            // Vt padded leading dim (R10-proven banks)
constexpr float SC = 0.18033688f;   // 0.125 * log2(e)

__global__ __launch_bounds__(256, 4)
void attn_mfma(const short* __restrict__ qkv, short* __restrict__ att)
{
    __shared__ __align__(16) short Ks[128 * 64];   // swizzled [key][d] 16 KB
    __shared__ __align__(16) short Vt[64 * LDV];   // permuted [d][key] 17 KB

    const int idx = blockIdx.x;
    const int xcd = idx & 7;
    const int j   = idx >> 3;                // 0..127
    const int bh  = xcd * 4 + (j & 3);
    const int s   = j >> 2;                  // 0..31
    const int qt  = (s < 8)  ? (31 - s)
                  : (s < 16) ? (s - 8)
                  : (s < 24) ? (39 - s)
                  :            (s - 16);
    const int b   = bh >> 4;
    const int h   = bh & 15;
    const int qbase = qt * 64;

    const int tid = threadIdx.x;
    const int w   = tid >> 6;
    const int l   = tid & 63;
    const int lk  = l & 15;
    const int lq  = l >> 4;

    const short* base = qkv + (size_t)b * T * 3072 + h * 64;

    // Q fragments (B-operand of S^T); lane owns q-row q_abs
    const int q_abs = qbase + w * 16 + lk;
    const short* qp = base + (size_t)q_abs * 3072 + lq * 8;
    const bf16x8 qf0 = *(const bf16x8*)qp;
    const bf16x8 qf1 = *(const bf16x8*)(qp + 32);

    // O^T accumulators: acc[dt][r] = O^T[d=dt*16+lq*4+r][q=lk]
    f32x4 acc_o[4];
#pragma unroll
    for (int dt = 0; dt < 4; ++dt) acc_o[dt] = (f32x4){0.f, 0.f, 0.f, 0.f};
    float m_run = -INFINITY;
    float l_run = 0.f;

    // K staging: dest row g+(l>>3), dest col (l&7)*8; source dim-block XOR'd
    const int krow   = l >> 3;
    const int kcolsw = 8 * ((l & 7) ^ (l >> 3));
    const int swz    = lk & 7;

    // V staging: thread owns key-group kg (4 keys), dims vd0..+8; writes at
    // permuted granule pcol so PV's b128 read sees the slot-ordered keys.
    const int kg   = tid & 31;
    const int vd0  = (tid >> 5) * 8;
    const int pcol = ((kg & 24) | ((kg & 3) << 1) | ((kg >> 2) & 1)) * 4;

    const int nkt = (qbase + 64 + 127) >> 7;
#pragma unroll 1
    for (int it = 0; it < nkt; ++it) {
        const int j0 = it * 128;
        __syncthreads();
#pragma unroll
        for (int rr = 0; rr < 4; ++rr) {
            const int g = w * 32 + rr * 8;
            gload_lds16(base + 1024 + (size_t)(j0 + g + krow) * 3072 + kcolsw, &Ks[g * 64]);
        }
        {
            const short* vp = base + 2048 + (size_t)(j0 + kg * 4) * 3072 + vd0;
            bf16x8 vv[4];
#pragma unroll
            for (int kk = 0; kk < 4; ++kk)
                vv[kk] = *(const bf16x8*)(vp + (size_t)kk * 3072);
#pragma unroll
            for (int d = 0; d < 8; ++d) {
                short4 pk;
                pk.x = vv[0][d]; pk.y = vv[1][d]; pk.z = vv[2][d]; pk.w = vv[3][d];
                *(short4*)&Vt[(vd0 + d) * LDV + pcol] = pk;
            }
        }
        __syncthreads();

        // --- S^T = K Q^T: s4[kt][r] = S[key = j0 + kt*16 + lq*4 + r][q = lk] ---
        f32x4 s4[8];
#pragma unroll
        for (int kt = 0; kt < 8; ++kt) {
            const int row = kt * 16 + lk;
            const bf16x8 kf0 = *(const bf16x8*)&Ks[row * 64 + 8 * (lq ^ swz)];
            const bf16x8 kf1 = *(const bf16x8*)&Ks[row * 64 + 8 * ((lq + 4) ^ swz)];
            f32x4 a = (f32x4){0.f, 0.f, 0.f, 0.f};
            a = __builtin_amdgcn_mfma_f32_16x16x32_bf16(kf0, qf0, a, 0, 0, 0);
            a = __builtin_amdgcn_mfma_f32_16x16x32_bf16(kf1, qf1, a, 0, 0, 0);
            s4[kt] = a;
        }

        // --- causal mask (last tile only; raw scores) ---
        if (it == nkt - 1) {
#pragma unroll
            for (int kt = 0; kt < 8; ++kt)
#pragma unroll
                for (int r = 0; r < 4; ++r)
                    if (j0 + kt * 16 + lq * 4 + r > q_abs) s4[kt][r] = -1e30f;
        }

        // --- online softmax: in-lane tree + 2 shfl hops ---
        float mx = s4[0][0];
#pragma unroll
        for (int kt = 0; kt < 8; ++kt)
#pragma unroll
            for (int r = 0; r < 4; ++r) mx = fmaxf(mx, s4[kt][r]);
        mx = fmaxf(mx, __shfl_xor(mx, 16));
        mx = fmaxf(mx, __shfl_xor(mx, 32));
        const float mn   = fmaxf(m_run, mx);
        const float corr = EXP2((m_run - mn) * SC);
        m_run = mn;
        const float nmc = -mn * SC;
#pragma unroll
        for (int kt = 0; kt < 8; ++kt)
#pragma unroll
            for (int r = 0; r < 4; ++r)
                s4[kt][r] = EXP2(fmaf(s4[kt][r], SC, nmc));
        float ps = 0.f;
#pragma unroll
        for (int kt = 0; kt < 8; ++kt)
            ps += ((s4[kt][0] + s4[kt][1]) + (s4[kt][2] + s4[kt][3]));
        ps += __shfl_xor(ps, 16);
        ps += __shfl_xor(ps, 32);
        l_run = l_run * corr + ps;

        // --- pack P rows to dwords ---
        unsigned int d0[8], d1[8];
#pragma unroll
        for (int kt = 0; kt < 8; ++kt) {
            d0[kt] = (unsigned int)(unsigned short)f2bf(s4[kt][0])
                   | ((unsigned int)(unsigned short)f2bf(s4[kt][1]) << 16);
            d1[kt] = (unsigned int)(unsigned short)f2bf(s4[kt][2])
                   | ((unsigned int)(unsigned short)f2bf(s4[kt][3]) << 16);
        }

#pragma unroll
        for (int dt = 0; dt < 4; ++dt)
#pragma unroll
            for (int r = 0; r < 4; ++r) acc_o[dt][r] *= corr;

        // --- O^T += V^T P^T: pf straight from registers; vf one b128 read
        //     (Vt granule permutation matches the slot->key map) ---
#pragma unroll
        for (int kc = 0; kc < 4; ++kc) {
            union { unsigned int u[4]; bf16x8 v; } up;
            up.u[0] = d0[kc * 2];
            up.u[1] = d1[kc * 2];
            up.u[2] = d0[kc * 2 + 1];
            up.u[3] = d1[kc * 2 + 1];
            const bf16x8 pf = up.v;
#pragma unroll
            for (int dt = 0; dt < 4; ++dt) {
                const bf16x8 vf = *(const bf16x8*)&Vt[(dt * 16 + lk) * LDV + kc * 32 + lq * 8];
                acc_o[dt] = __builtin_amdgcn_mfma_f32_16x16x32_bf16(vf, pf, acc_o[dt], 0, 0, 0);
            }
        }
    }

    // --- epilogue: O[q][d] = O^T[d][q]/l ---
    const float inv = 1.f / l_run;
    short* op = att + ((size_t)(b * T + q_abs)) * 1024 + h * 64;
#pragma unroll
    for (int dt = 0; dt < 4; ++dt) {
        short4 pk;
        pk.x = f2bf(acc_o[dt][0] * inv);
        pk.y = f2bf(acc_o[dt][1] * inv);
        pk.z = f2bf(acc_o[dt][2] * inv);
        pk.w = f2bf(acc_o[dt][3] * inv);
        *(short4*)(op + dt * 16 + lq * 4) = pk;
    }
}

// ---------------------------------------------------------------------------
extern "C" void kernel_launch(void* const* d_in, const int* in_sizes, int n_in,
                              void* d_out, int out_size, void* d_ws, size_t ws_size,
                              hipStream_t stream)
{
    const float* x      = (const float*)d_in[0];   // [B,T,C]
    const float* w_qkv  = (const float*)d_in[1];   // [C,3C]
    const float* b_qkv  = (const float*)d_in[2];   // [3C]
    const float* w_proj = (const float*)d_in[3];   // [C,C]
    const float* b_proj = (const float*)d_in[4];   // [C]
    float* out = (float*)d_out;                    // [B,T,C] fp32

    short* xb     = (short*)d_ws;                        //  8 MB
    short* wqkvt  = xb     + (size_t)M * C;              //  6 MB  [3072][1024]
    short* wprojt = wqkvt  + (size_t)NQKV * C;           //  2 MB  [1024][1024]
    short* qkvb   = wprojt + (size_t)C * C;              // 24 MB  [4096][3072]
    short* attb   = qkvb   + (size_t)M * NQKV;           //  8 MB  [4096][1024]

    prep_all<<<8192, 256, 0, stream>>>(x, xb, w_qkv, wqkvt, w_proj, wprojt);
    gemm_mfma<<<dim3(NQKV / 128, M / 128), 256, 0, stream>>>(xb, wqkvt, b_qkv, qkvb, NQKV, C);
    attn_mfma<<<1024, 256, 0, stream>>>(qkvb, attb);
    gemm_mfma_proj<<<dim3(C / 128, M / 64), 256, 0, stream>>>(attb, wprojt, b_proj, out, C, C);
}